// Round 14
// baseline (134.336 us; speedup 1.0000x reference)
//
#include <hip/hip_runtime.h>
#include <hip/hip_bf16.h>

// Problem constants
#define NB 8
#define NH 8
#define LQ 1024
#define LK 1024
#define DD 64
#define EC 0.18033688011112042f      // (1/8) * log2(e)
#define OUT0_SIZE (8ull*8*1024*64)   // output [B,H,LQ,D]

typedef __bf16 bf16x8 __attribute__((ext_vector_type(8)));
typedef __bf16 bf16x4 __attribute__((ext_vector_type(4)));
typedef float  f32x4  __attribute__((ext_vector_type(4)));
typedef unsigned int u32x2 __attribute__((ext_vector_type(2)));

static __device__ __forceinline__ __bf16 f2b(float f) {
    unsigned u = __builtin_bit_cast(unsigned, f);
    unsigned r = (u + 0x7fffu + ((u >> 16) & 1u)) >> 16;
    return __builtin_bit_cast(__bf16, (unsigned short)r);
}
static __device__ __forceinline__ unsigned bpack(float a, float b) {
    return (unsigned)__builtin_bit_cast(unsigned short, f2b(a))
         | ((unsigned)__builtin_bit_cast(unsigned short, f2b(b)) << 16);
}
// direct global->LDS DMA, 16B per lane. LDS dest = uniform base + lane*16.
static __device__ __forceinline__ void gload16(const void* g, void* l) {
    __builtin_amdgcn_global_load_lds(
        (const __attribute__((address_space(1))) void*)g,
        (__attribute__((address_space(3))) void*)l, 16, 0, 0);
}

// ---------------------------------------------------------------------------
// K0a: independent 64x64x64 f32 products: P1=WA@WB, P2=WBt@WAt, Wv=Wav@Wbv
// ---------------------------------------------------------------------------
__global__ __launch_bounds__(256) void fold_pairs(
        const float* __restrict__ pWA, const float* __restrict__ pWB,
        const float* __restrict__ pWBt, const float* __restrict__ pWAt,
        const float* __restrict__ pWav, const float* __restrict__ pWbv,
        float* __restrict__ P1, float* __restrict__ P2, float* __restrict__ Wv) {
    __shared__ float AT[64*68];
    __shared__ float Bl[64*64];
    const int h = blockIdx.x / 3;
    const int which = blockIdx.x - h*3;
    const int t = threadIdx.x;
    const float *A, *B; float* C;
    if (which == 0)      { A = pWA  + h*4096; B = pWB  + h*4096; C = P1 + h*4096; }
    else if (which == 1) { A = pWBt + h*4096; B = pWAt + h*4096; C = P2 + h*4096; }
    else                 { A = pWav + h*4096; B = pWbv + h*4096; C = Wv + h*4096; }

    for (int i = t; i < 4096; i += 256) {
        int r = i >> 6, c = i & 63;
        AT[c*68 + r] = A[i];
        Bl[i] = B[i];
    }
    __syncthreads();
    const int r0 = (t >> 4) * 4, j0 = (t & 15) * 4;
    float acc[4][4] = {};
    #pragma unroll 8
    for (int k = 0; k < 64; ++k) {
        f32x4 a = *(const f32x4*)&AT[k*68 + r0];
        f32x4 b = *(const f32x4*)&Bl[k*64 + j0];
        #pragma unroll
        for (int i = 0; i < 4; ++i)
            #pragma unroll
            for (int j = 0; j < 4; ++j) acc[i][j] += a[i] * b[j];
    }
    #pragma unroll
    for (int i = 0; i < 4; ++i) {
        f32x4 o = { acc[i][0], acc[i][1], acc[i][2], acc[i][3] };
        *(f32x4*)&C[(r0 + i)*64 + j0] = o;
    }
}

// K0b: W = P1 @ P2
__global__ __launch_bounds__(256) void fold_final(
        const float* __restrict__ P1, const float* __restrict__ P2,
        float* __restrict__ Wout) {
    __shared__ float AT[64*68];
    __shared__ float Bl[64*64];
    const int h = blockIdx.x;
    const int t = threadIdx.x;
    for (int i = t; i < 4096; i += 256) {
        int r = i >> 6, c = i & 63;
        AT[c*68 + r] = P1[h*4096 + i];
        Bl[i] = P2[h*4096 + i];
    }
    __syncthreads();
    const int r0 = (t >> 4) * 4, j0 = (t & 15) * 4;
    float acc[4][4] = {};
    #pragma unroll 8
    for (int k = 0; k < 64; ++k) {
        f32x4 a = *(const f32x4*)&AT[k*68 + r0];
        f32x4 b = *(const f32x4*)&Bl[k*64 + j0];
        #pragma unroll
        for (int i = 0; i < 4; ++i)
            #pragma unroll
            for (int j = 0; j < 4; ++j) acc[i][j] += a[i] * b[j];
    }
    #pragma unroll
    for (int i = 0; i < 4; ++i) {
        f32x4 o = { acc[i][0], acc[i][1], acc[i][2], acc[i][3] };
        *(f32x4*)&Wout[h*4096 + (r0 + i)*64 + j0] = o;
    }
}

// ---------------------------------------------------------------------------
// K1 (merged prepass): blockIdx.y selects qW / qtT / vWT production.
// vWT is TILED: [bh][mchunk(16)][c(64)][mlocal(64)].
// ---------------------------------------------------------------------------
__global__ __launch_bounds__(256) void prepass(
        const float* __restrict__ q, const float* __restrict__ W,
        const float* __restrict__ qt, const float* __restrict__ v,
        const float* __restrict__ Wv,
        __bf16* __restrict__ qW, __bf16* __restrict__ qtT,
        __bf16* __restrict__ vWT) {
    __shared__ float smem[8448];
    const int bh = blockIdx.x;
    const int by = blockIdx.y;
    const int batch = bh >> 3, h = bh & 7;
    const int t = threadIdx.x;

    if (by < 16) {
        float* qT = smem;            // [c][r] 64x68
        float* Wl = smem + 4352;     // [c][j] 64x64
        const int a0 = by * 64;
        for (int i = t; i < 4096; i += 256) {
            int r = i >> 6, c = i & 63;
            Wl[i] = W[h*4096 + i];
            qT[c*68 + r] = q[(((size_t)batch*LQ + a0 + r)*NH + h)*DD + c];
        }
        __syncthreads();
        const int r0 = (t >> 4) * 4, j0 = (t & 15) * 4;
        float acc[4][4] = {};
        #pragma unroll 8
        for (int c = 0; c < 64; ++c) {
            f32x4 a = *(const f32x4*)&qT[c*68 + r0];
            f32x4 b = *(const f32x4*)&Wl[c*64 + j0];
            #pragma unroll
            for (int i = 0; i < 4; ++i)
                #pragma unroll
                for (int j = 0; j < 4; ++j) acc[i][j] += a[i] * b[j];
        }
        #pragma unroll
        for (int i = 0; i < 4; ++i) {
            bf16x4 o;
            #pragma unroll
            for (int j = 0; j < 4; ++j) o[j] = f2b(acc[i][j]);
            *(bf16x4*)&qW[((size_t)bh*LQ + a0 + r0 + i)*DD + j0] = o;
        }
    } else if (by < 24) {
        float* tile = smem;          // [j][n] 64x132
        const int n0 = (by - 16) * 128;
        #pragma unroll
        for (int it = 0; it < 8; ++it) {
            int idx = (t + 256*it) * 4;
            int j = idx >> 7, n = idx & 127;
            *(f32x4*)&tile[j*132 + n] = *(const f32x4*)&qt[((size_t)bh*DD + j)*LK + n0 + n];
        }
        __syncthreads();
        const int j0 = (t & 15) * 4;
        #pragma unroll
        for (int it = 0; it < 8; ++it) {
            int n = (t >> 4) + 16*it;
            bf16x4 o;
            #pragma unroll
            for (int i = 0; i < 4; ++i) o[i] = f2b(tile[(j0 + i)*132 + n]);
            *(bf16x4*)&qtT[((size_t)bh*LK + n0 + n)*DD + j0] = o;
        }
    } else {
        float* vT  = smem;           // [n][m] 64x68
        float* Wvl = smem + 4352;    // [n][c] 64x64
        const int mb0 = (by - 24) * 64;
        const int mb  = by - 24;     // m-chunk index 0..15
        for (int i = t; i < 4096; i += 256) {
            int r = i >> 6, c = i & 63;     // r = m-row, c = n
            Wvl[i] = Wv[h*4096 + i];
            vT[c*68 + r] = v[(((size_t)batch*LK + mb0 + r)*NH + h)*DD + c];
        }
        __syncthreads();
        const int c0 = (t >> 4) * 4, m0 = (t & 15) * 4;
        float acc[4][4] = {};               // [c][m]
        #pragma unroll 8
        for (int n = 0; n < 64; ++n) {
            f32x4 wv = *(const f32x4*)&Wvl[n*64 + c0];
            f32x4 vv = *(const f32x4*)&vT[n*68 + m0];
            #pragma unroll
            for (int ci = 0; ci < 4; ++ci)
                #pragma unroll
                for (int mi = 0; mi < 4; ++mi) acc[ci][mi] += wv[ci] * vv[mi];
        }
        #pragma unroll
        for (int ci = 0; ci < 4; ++ci) {
            bf16x4 o;
            #pragma unroll
            for (int mi = 0; mi < 4; ++mi) o[mi] = f2b(acc[ci][mi]);
            *(bf16x4*)&vWT[((((size_t)bh*16 + mb)*64) + c0 + ci)*64 + m0] = o;
        }
    }
}

// ---------------------------------------------------------------------------
// K4: split-loop one-pass attn with COUNTED-VMCNT barriers in loop B.
// Loop A: K-only (QK MFMA + exp -> ppk + rsum), __syncthreads per chunk.
// Loop B: per chunk: V-DMA -> sched_barrier -> P stores -> PV MFMA ->
//   s_waitcnt vmcnt(4) (drains only this chunk's 4 DMA; the 4 NT stores
//   stay in flight) -> raw s_barrier. Stores stream under compute instead
//   of being drained at every barrier (the R13 regression mechanism).
// ---------------------------------------------------------------------------
__global__ __launch_bounds__(256) void attn_kernel(
        const __bf16* __restrict__ qW, const __bf16* __restrict__ qtT,
        const __bf16* __restrict__ vWT, float* __restrict__ out) {
    __shared__ __align__(16) char smem[61696];
    __bf16* KV   = (__bf16*)(smem);             // [2 nh][2 db][64][64] : 32768 B
    __bf16* El   = (__bf16*)(smem + 32768);     // [4][16][80] : 10240 B
    float*  Pt0  = (float*) (smem + 43008);     // [4][16][72] : 18432 B
    float*  rsb  = (float*) (smem + 61440);     // [2][2][16]  : 256 B
    float*  Obuf = (float*) (smem);             // epilogue alias [32][72]

    const int bid = blockIdx.x;
    const int xcd = bid & 7, s = bid >> 3;
    const int bh  = xcd * 8 + (s >> 5);
    const int a0  = (s & 31) * 32;
    const int t   = threadIdx.x;
    const int w   = t >> 6, l = t & 63;
    const int lg  = l & 15, g = l >> 4;
    const int strip = w & 1, nh = w >> 1;
    const int qbase = a0 + strip * 16;
    const int n0w   = nh * 512;
    const int srow = l >> 3, scol = l & 7;
    const int swz  = scol ^ srow;              // inverse-swizzled source block

    const __bf16* qtb = qtT + (size_t)bh * LK * DD;
    const __bf16* vwb = vWT + (size_t)bh * LK * DD;   // tiled [16][64][64]

    __bf16* eldw = El + (size_t)w * 16 * 80;
    float*  ptw  = Pt0 + (size_t)w * 16 * 72;

    // B fragments (N = q)
    const bf16x8* qWp = reinterpret_cast<const bf16x8*>(qW + ((size_t)bh*LQ + qbase + lg)*DD);
    bf16x8 bfrag0 = qWp[g];
    bf16x8 bfrag1 = qWp[g + 4];

    // swizzled ds_read element offsets (lane-constant)
    const int sw0 = (g ^ (lg & 7)) * 8;
    const int sw1 = ((g + 4) ^ (lg & 7)) * 8;

    // each wave stages 32 rows (4 x 8-row 1KB loads) of its nh's tile
#define STAGE_K(NC, DB)                                                        \
    {                                                                          \
        const __bf16* src = qtb + (size_t)(nh*512 + (NC)*64 + strip*32 + srow)*64 + swz*8; \
        __bf16* dst = KV + nh*8192 + (DB)*4096 + strip*2048;                   \
        _Pragma("unroll")                                                      \
        for (int i = 0; i < 4; ++i)                                            \
            gload16(src + (size_t)i*512, dst + i*512);                         \
    }
#define STAGE_V(NC, DB)                                                        \
    {                                                                          \
        const __bf16* src = vwb + (size_t)(nh*8 + (NC))*4096 + (size_t)(strip*32 + srow)*64 + swz*8; \
        __bf16* dst = KV + nh*8192 + (DB)*4096 + strip*2048;                   \
        _Pragma("unroll")                                                      \
        for (int i = 0; i < 4; ++i)                                            \
            gload16(src + (size_t)i*512, dst + i*512);                         \
    }

    // ---- Loop A: QK + exp + rsum (K only) ----
    STAGE_K(0, 0);
    __syncthreads();

    u32x2 ppk[8][4];               // packed unnormalized exp(S) (bf16 x4)
    float rs0 = 0.f, rs1 = 0.f, rs2 = 0.f, rs3 = 0.f;

    #pragma unroll
    for (int nc = 0; nc < 8; ++nc) {
        const int db = nc & 1;
        if (nc < 7) { STAGE_K(nc + 1, db ^ 1); }
        else        { STAGE_V(0, db ^ 1); }     // V chunk 0 into freed slot
        const __bf16* Kcur = KV + nh*8192 + db*4096;
        f32x4 accs[4];
        #pragma unroll
        for (int sub = 0; sub < 4; ++sub) {
            const __bf16* kr = Kcur + (sub*16 + lg)*64;
            bf16x8 a0 = *(const bf16x8*)&kr[sw0];
            bf16x8 a1 = *(const bf16x8*)&kr[sw1];
            f32x4 acc = {0.f, 0.f, 0.f, 0.f};
            acc = __builtin_amdgcn_mfma_f32_16x16x32_bf16(a0, bfrag0, acc, 0, 0, 0);
            acc = __builtin_amdgcn_mfma_f32_16x16x32_bf16(a1, bfrag1, acc, 0, 0, 0);
            accs[sub] = acc;
        }
        #pragma unroll
        for (int sub = 0; sub < 4; ++sub) {
            float p0 = __builtin_exp2f(accs[sub][0] * EC);
            float p1 = __builtin_exp2f(accs[sub][1] * EC);
            float p2 = __builtin_exp2f(accs[sub][2] * EC);
            float p3 = __builtin_exp2f(accs[sub][3] * EC);
            rs0 += p0; rs1 += p1; rs2 += p2; rs3 += p3;
            u32x2 pk;
            pk.x = bpack(p0, p1);
            pk.y = bpack(p2, p3);
            ppk[nc][sub] = pk;
        }
        __syncthreads();
    }

    // ---- cross-wave rsum reduce ----
    float rsum = (rs0 + rs1) + (rs2 + rs3);
    rsum += __shfl_xor(rsum, 16);
    rsum += __shfl_xor(rsum, 32);
    if (l < 16) rsb[(nh*2 + strip)*16 + l] = rsum;
    __syncthreads();
    const float rinv = 1.0f / (rsb[(0*2 + strip)*16 + lg] + rsb[(1*2 + strip)*16 + lg]);

    // ---- Loop B: V DMA + P stores + PV MFMA, counted-vmcnt barriers ----
    const int rr = l >> 4, cc = l & 15;
    float* attnb = out + OUT0_SIZE + ((size_t)bh << 20);
    f32x4 oacc[4];
    #pragma unroll
    for (int ct = 0; ct < 4; ++ct) oacc[ct] = f32x4{0.f, 0.f, 0.f, 0.f};

    #pragma unroll
    for (int nc = 0; nc < 8; ++nc) {
        const int db = nc & 1;
        // (1) DMA first — oldest in the vmcnt FIFO
        if (nc < 7) { STAGE_V(nc + 1, db ^ 1); }
        __builtin_amdgcn_sched_barrier(0);   // pin DMA ahead of the stores
        const int nbase = n0w + nc*64;
        // (2) P staging + NT stores (these may stay in flight past the barrier)
        #pragma unroll
        for (int sub = 0; sub < 4; ++sub) {
            unsigned lo = ppk[nc][sub].x, hi = ppk[nc][sub].y;
            f32x4 ps;
            ps[0] = __builtin_bit_cast(float, lo << 16) * rinv;
            ps[1] = __builtin_bit_cast(float, lo & 0xffff0000u) * rinv;
            ps[2] = __builtin_bit_cast(float, hi << 16) * rinv;
            ps[3] = __builtin_bit_cast(float, hi & 0xffff0000u) * rinv;
            *(f32x4*)&ptw[lg*72 + sub*16 + g*4] = ps;
            *(u32x2*)&eldw[lg*80 + sub*16 + g*4] = ppk[nc][sub];
        }
        #pragma unroll
        for (int it = 0; it < 4; ++it) {
            int row = it*4 + rr;
            f32x4 pp = *(const f32x4*)&ptw[row*72 + cc*4];
            __builtin_nontemporal_store(pp,
                (f32x4*)&attnb[((size_t)(qbase + row) << 10) + nbase + cc*4]);
        }
        // (3) PV MFMAs
        const __bf16* er = &eldw[lg*80];
        bf16x8 pf0 = *(const bf16x8*)&er[g*8];
        bf16x8 pf1 = *(const bf16x8*)&er[g*8 + 32];
        const __bf16* Vcur = KV + nh*8192 + db*4096;
        #pragma unroll
        for (int ct = 0; ct < 4; ++ct) {
            const __bf16* vr = Vcur + (ct*16 + lg)*64;
            bf16x8 v0 = *(const bf16x8*)&vr[sw0];
            bf16x8 v1 = *(const bf16x8*)&vr[sw1];
            oacc[ct] = __builtin_amdgcn_mfma_f32_16x16x32_bf16(v0, pf0, oacc[ct], 0, 0, 0);
            oacc[ct] = __builtin_amdgcn_mfma_f32_16x16x32_bf16(v1, pf1, oacc[ct], 0, 0, 0);
        }
        // (4) counted-vmcnt barrier: drain this chunk's 4 DMA, keep stores
        //     in flight. lgkmcnt(0) covers cross-wave LDS ordering.
        asm volatile("s_waitcnt vmcnt(4) lgkmcnt(0)" ::: "memory");
        __builtin_amdgcn_s_barrier();
        __builtin_amdgcn_sched_barrier(0);   // nothing crosses the barrier
    }

    // ---- O: scale, cross-wave reduce (Obuf aliases KV region), NT store ----
    #pragma unroll
    for (int ct = 0; ct < 4; ++ct) oacc[ct] *= rinv;

    if (nh == 1) {
        #pragma unroll
        for (int ct = 0; ct < 4; ++ct)
            *(f32x4*)&Obuf[(strip*16 + lg)*72 + ct*16 + g*4] = oacc[ct];
    }
    __syncthreads();
    if (nh == 0) {
        #pragma unroll
        for (int ct = 0; ct < 4; ++ct) {
            f32x4 o = *(const f32x4*)&Obuf[(strip*16 + lg)*72 + ct*16 + g*4];
            o = o + oacc[ct];
            *(f32x4*)&Obuf[(strip*16 + lg)*72 + ct*16 + g*4] = o;
        }
    }
    __syncthreads();
    #pragma unroll
    for (int it = 0; it < 2; ++it) {
        int row = it*16 + w*4 + rr;           // 0..31
        f32x4 o = *(const f32x4*)&Obuf[row*72 + cc*4];
        __builtin_nontemporal_store(o,
            (f32x4*)&out[(((size_t)bh*LQ + a0 + row) << 6) + cc*4]);
    }
#undef STAGE_K
#undef STAGE_V
}

// ---------------------------------------------------------------------------
extern "C" void kernel_launch(void* const* d_in, const int* in_sizes, int n_in,
                              void* d_out, int out_size, void* d_ws, size_t ws_size,
                              hipStream_t stream) {
    const float* q   = (const float*)d_in[0];
    const float* WA  = (const float*)d_in[1];
    const float* WB  = (const float*)d_in[2];
    const float* WAt = (const float*)d_in[3];
    const float* WBt = (const float*)d_in[4];
    const float* Wav = (const float*)d_in[5];
    const float* Wbv = (const float*)d_in[6];
    const float* qt  = (const float*)d_in[7];
    const float* v   = (const float*)d_in[8];
    float* out = (float*)d_out;

    char* ws = (char*)d_ws;
    float*  W    = (float*)(ws);                          // 128 KB
    float*  Wv   = (float*)(ws + 131072);                 // 128 KB
    __bf16* qW   = (__bf16*)(ws + 262144);                // 8 MB
    __bf16* qtT  = (__bf16*)(ws + 262144 + 8388608);      // 8 MB
    __bf16* vWT  = (__bf16*)(ws + 262144 + 2*8388608);    // 8 MB (tiled)
    float*  P1   = (float*)(ws + 262144);                 // 128 KB (aliases qW)
    float*  P2   = (float*)(ws + 262144 + 131072);        // 128 KB

    hipLaunchKernelGGL(fold_pairs, dim3(24), dim3(256), 0, stream,
                       WA, WB, WBt, WAt, Wav, Wbv, P1, P2, Wv);
    hipLaunchKernelGGL(fold_final, dim3(8),  dim3(256), 0, stream, P1, P2, W);
    hipLaunchKernelGGL(prepass,    dim3(64, 40), dim3(256), 0, stream,
                       q, W, qt, v, Wv, qW, qtT, vWT);
    hipLaunchKernelGGL(attn_kernel, dim3(2048), dim3(256), 0, stream,
                       qW, qtT, vWT, out);
}

// Round 16
// 107.993 us; speedup vs baseline: 1.2439x; 1.2439x over previous
//
#include <hip/hip_runtime.h>
#include <hip/hip_bf16.h>

// Problem constants
#define NB 8
#define NH 8
#define LQ 1024
#define LK 1024
#define DD 64
#define EC 0.18033688011112042f      // (1/8) * log2(e)
#define OUT0_SIZE (8ull*8*1024*64)   // output [B,H,LQ,D]

typedef __bf16 bf16x8 __attribute__((ext_vector_type(8)));
typedef __bf16 bf16x4 __attribute__((ext_vector_type(4)));
typedef float  f32x4  __attribute__((ext_vector_type(4)));
typedef unsigned int u32x2 __attribute__((ext_vector_type(2)));

static __device__ __forceinline__ __bf16 f2b(float f) {
    unsigned u = __builtin_bit_cast(unsigned, f);
    unsigned r = (u + 0x7fffu + ((u >> 16) & 1u)) >> 16;
    return __builtin_bit_cast(__bf16, (unsigned short)r);
}
static __device__ __forceinline__ unsigned bpack(float a, float b) {
    return (unsigned)__builtin_bit_cast(unsigned short, f2b(a))
         | ((unsigned)__builtin_bit_cast(unsigned short, f2b(b)) << 16);
}
// direct global->LDS DMA, 16B per lane. LDS dest = uniform base + lane*16.
static __device__ __forceinline__ void gload16(const void* g, void* l) {
    __builtin_amdgcn_global_load_lds(
        (const __attribute__((address_space(1))) void*)g,
        (__attribute__((address_space(3))) void*)l, 16, 0, 0);
}

// ---------------------------------------------------------------------------
// K0a: independent 64x64x64 f32 products: P1=WA@WB, P2=WBt@WAt, Wv=Wav@Wbv
// ---------------------------------------------------------------------------
__global__ __launch_bounds__(256) void fold_pairs(
        const float* __restrict__ pWA, const float* __restrict__ pWB,
        const float* __restrict__ pWBt, const float* __restrict__ pWAt,
        const float* __restrict__ pWav, const float* __restrict__ pWbv,
        float* __restrict__ P1, float* __restrict__ P2, float* __restrict__ Wv) {
    __shared__ float AT[64*68];
    __shared__ float Bl[64*64];
    const int h = blockIdx.x / 3;
    const int which = blockIdx.x - h*3;
    const int t = threadIdx.x;
    const float *A, *B; float* C;
    if (which == 0)      { A = pWA  + h*4096; B = pWB  + h*4096; C = P1 + h*4096; }
    else if (which == 1) { A = pWBt + h*4096; B = pWAt + h*4096; C = P2 + h*4096; }
    else                 { A = pWav + h*4096; B = pWbv + h*4096; C = Wv + h*4096; }

    for (int i = t; i < 4096; i += 256) {
        int r = i >> 6, c = i & 63;
        AT[c*68 + r] = A[i];
        Bl[i] = B[i];
    }
    __syncthreads();
    const int r0 = (t >> 4) * 4, j0 = (t & 15) * 4;
    float acc[4][4] = {};
    #pragma unroll 8
    for (int k = 0; k < 64; ++k) {
        f32x4 a = *(const f32x4*)&AT[k*68 + r0];
        f32x4 b = *(const f32x4*)&Bl[k*64 + j0];
        #pragma unroll
        for (int i = 0; i < 4; ++i)
            #pragma unroll
            for (int j = 0; j < 4; ++j) acc[i][j] += a[i] * b[j];
    }
    #pragma unroll
    for (int i = 0; i < 4; ++i) {
        f32x4 o = { acc[i][0], acc[i][1], acc[i][2], acc[i][3] };
        *(f32x4*)&C[(r0 + i)*64 + j0] = o;
    }
}

// K0b: W = P1 @ P2
__global__ __launch_bounds__(256) void fold_final(
        const float* __restrict__ P1, const float* __restrict__ P2,
        float* __restrict__ Wout) {
    __shared__ float AT[64*68];
    __shared__ float Bl[64*64];
    const int h = blockIdx.x;
    const int t = threadIdx.x;
    for (int i = t; i < 4096; i += 256) {
        int r = i >> 6, c = i & 63;
        AT[c*68 + r] = P1[h*4096 + i];
        Bl[i] = P2[h*4096 + i];
    }
    __syncthreads();
    const int r0 = (t >> 4) * 4, j0 = (t & 15) * 4;
    float acc[4][4] = {};
    #pragma unroll 8
    for (int k = 0; k < 64; ++k) {
        f32x4 a = *(const f32x4*)&AT[k*68 + r0];
        f32x4 b = *(const f32x4*)&Bl[k*64 + j0];
        #pragma unroll
        for (int i = 0; i < 4; ++i)
            #pragma unroll
            for (int j = 0; j < 4; ++j) acc[i][j] += a[i] * b[j];
    }
    #pragma unroll
    for (int i = 0; i < 4; ++i) {
        f32x4 o = { acc[i][0], acc[i][1], acc[i][2], acc[i][3] };
        *(f32x4*)&Wout[h*4096 + (r0 + i)*64 + j0] = o;
    }
}

// ---------------------------------------------------------------------------
// K1 (merged prepass): blockIdx.y selects qW / qtT / vWT production.
// vWT is TILED: [bh][mchunk(16)][c(64)][mlocal(64)].
// ---------------------------------------------------------------------------
__global__ __launch_bounds__(256) void prepass(
        const float* __restrict__ q, const float* __restrict__ W,
        const float* __restrict__ qt, const float* __restrict__ v,
        const float* __restrict__ Wv,
        __bf16* __restrict__ qW, __bf16* __restrict__ qtT,
        __bf16* __restrict__ vWT) {
    __shared__ float smem[8448];
    const int bh = blockIdx.x;
    const int by = blockIdx.y;
    const int batch = bh >> 3, h = bh & 7;
    const int t = threadIdx.x;

    if (by < 16) {
        float* qT = smem;            // [c][r] 64x68
        float* Wl = smem + 4352;     // [c][j] 64x64
        const int a0 = by * 64;
        for (int i = t; i < 4096; i += 256) {
            int r = i >> 6, c = i & 63;
            Wl[i] = W[h*4096 + i];
            qT[c*68 + r] = q[(((size_t)batch*LQ + a0 + r)*NH + h)*DD + c];
        }
        __syncthreads();
        const int r0 = (t >> 4) * 4, j0 = (t & 15) * 4;
        float acc[4][4] = {};
        #pragma unroll 8
        for (int c = 0; c < 64; ++c) {
            f32x4 a = *(const f32x4*)&qT[c*68 + r0];
            f32x4 b = *(const f32x4*)&Wl[c*64 + j0];
            #pragma unroll
            for (int i = 0; i < 4; ++i)
                #pragma unroll
                for (int j = 0; j < 4; ++j) acc[i][j] += a[i] * b[j];
        }
        #pragma unroll
        for (int i = 0; i < 4; ++i) {
            bf16x4 o;
            #pragma unroll
            for (int j = 0; j < 4; ++j) o[j] = f2b(acc[i][j]);
            *(bf16x4*)&qW[((size_t)bh*LQ + a0 + r0 + i)*DD + j0] = o;
        }
    } else if (by < 24) {
        float* tile = smem;          // [j][n] 64x132
        const int n0 = (by - 16) * 128;
        #pragma unroll
        for (int it = 0; it < 8; ++it) {
            int idx = (t + 256*it) * 4;
            int j = idx >> 7, n = idx & 127;
            *(f32x4*)&tile[j*132 + n] = *(const f32x4*)&qt[((size_t)bh*DD + j)*LK + n0 + n];
        }
        __syncthreads();
        const int j0 = (t & 15) * 4;
        #pragma unroll
        for (int it = 0; it < 8; ++it) {
            int n = (t >> 4) + 16*it;
            bf16x4 o;
            #pragma unroll
            for (int i = 0; i < 4; ++i) o[i] = f2b(tile[(j0 + i)*132 + n]);
            *(bf16x4*)&qtT[((size_t)bh*LK + n0 + n)*DD + j0] = o;
        }
    } else {
        float* vT  = smem;           // [n][m] 64x68
        float* Wvl = smem + 4352;    // [n][c] 64x64
        const int mb0 = (by - 24) * 64;
        const int mb  = by - 24;     // m-chunk index 0..15
        for (int i = t; i < 4096; i += 256) {
            int r = i >> 6, c = i & 63;     // r = m-row, c = n
            Wvl[i] = Wv[h*4096 + i];
            vT[c*68 + r] = v[(((size_t)batch*LK + mb0 + r)*NH + h)*DD + c];
        }
        __syncthreads();
        const int c0 = (t >> 4) * 4, m0 = (t & 15) * 4;
        float acc[4][4] = {};               // [c][m]
        #pragma unroll 8
        for (int n = 0; n < 64; ++n) {
            f32x4 wv = *(const f32x4*)&Wvl[n*64 + c0];
            f32x4 vv = *(const f32x4*)&vT[n*68 + m0];
            #pragma unroll
            for (int ci = 0; ci < 4; ++ci)
                #pragma unroll
                for (int mi = 0; mi < 4; ++mi) acc[ci][mi] += wv[ci] * vv[mi];
        }
        // tiled layout: [bh][mb][c][mlocal]
        #pragma unroll
        for (int ci = 0; ci < 4; ++ci) {
            bf16x4 o;
            #pragma unroll
            for (int mi = 0; mi < 4; ++mi) o[mi] = f2b(acc[ci][mi]);
            *(bf16x4*)&vWT[((((size_t)bh*16 + mb)*64) + c0 + ci)*64 + m0] = o;
        }
    }
}

// ---------------------------------------------------------------------------
// K4: one-pass fused attn; K/V staged via global_load_lds (16B DMA) into
// double-buffered UNPADDED [64][64] LDS tiles with both-sides XOR swizzle
// (rule #21: linear DMA dest + inverse-swizzled per-lane GLOBAL source +
// swizzled ds_read). One barrier per chunk (syncthreads drains vmcnt).
// Epilogue Pt/Obuf alias the K staging region (disjoint lifetimes).
// LDS 76KB -> 2 blocks/CU. Deferred normalization as in R9/R10.
// ---------------------------------------------------------------------------
__global__ __launch_bounds__(256) void attn_kernel(
        const __bf16* __restrict__ qW, const __bf16* __restrict__ qtT,
        const __bf16* __restrict__ vWT, float* __restrict__ out) {
    __shared__ __align__(16) char smem[76032];
    __bf16* Kb   = (__bf16*)(smem);             // [2 nh][2 db][64][64] : 32768 B
    __bf16* Vb   = (__bf16*)(smem + 32768);     // [2 nh][2 db][64][64] : 32768 B
    __bf16* El   = (__bf16*)(smem + 65536);     // [4][16][80]          : 10240 B
    float*  rsb  = (float*) (smem + 75776);     // [2][2][16]           : 256 B
    // epilogue aliases (after final main-loop barrier):
    float*  Pt0  = (float*) (smem);             // [4][16][72] : 18432 B
    float*  Obuf = (float*) (smem + 18432);     // [32][72]    : 9216 B

    const int bid = blockIdx.x;
    const int xcd = bid & 7, s = bid >> 3;
    const int bh  = xcd * 8 + (s >> 5);
    const int a0  = (s & 31) * 32;
    const int t   = threadIdx.x;
    const int w   = t >> 6, l = t & 63;
    const int lg  = l & 15, g = l >> 4;
    const int strip = w & 1, nh = w >> 1;
    const int qbase = a0 + strip * 16;
    const int n0w   = nh * 512;
    const int srow = l >> 3, scol = l & 7;
    const int swz  = scol ^ srow;              // inverse-swizzled source block

    const __bf16* qtb = qtT + (size_t)bh * LK * DD;
    const __bf16* vwb = vWT + (size_t)bh * LK * DD;   // tiled [16][64][64]

    __bf16* Kbw  = Kb + (size_t)nh * 8192;
    __bf16* Vbw  = Vb + (size_t)nh * 8192;
    __bf16* eldw = El + (size_t)w * 16 * 80;

    // B fragments (N = q)
    const bf16x8* qWp = reinterpret_cast<const bf16x8*>(qW + ((size_t)bh*LQ + qbase + lg)*DD);
    bf16x8 bfrag0 = qWp[g];
    bf16x8 bfrag1 = qWp[g + 4];

    const __bf16* gK = qtb + (size_t)(nh*512)*64;
    const __bf16* gV = vwb;

    // swizzled ds_read element offsets (lane-constant)
    const int sw0 = (g ^ (lg & 7)) * 8;
    const int sw1 = ((g + 4) ^ (lg & 7)) * 8;

#define STAGE(NC, DB)                                                          \
    if ((w & 1) == 0) {                                                        \
        const __bf16* src = gK + (size_t)((NC)*64 + srow)*64 + swz*8;          \
        __bf16* dst = Kbw + (DB)*4096;                                         \
        _Pragma("unroll")                                                      \
        for (int i = 0; i < 8; ++i)                                            \
            gload16(src + (size_t)i*512, dst + i*512);                         \
    } else {                                                                   \
        const __bf16* src = gV + (size_t)(nh*8 + (NC))*4096 + (size_t)srow*64 + swz*8; \
        __bf16* dst = Vbw + (DB)*4096;                                         \
        _Pragma("unroll")                                                      \
        for (int i = 0; i < 8; ++i)                                            \
            gload16(src + (size_t)i*512, dst + i*512);                         \
    }

    // prologue: stage chunk 0 into db=0
    STAGE(0, 0);
    __syncthreads();

    u32x2 ppk[8][4];               // packed unnormalized exp(S) (bf16 x4)
    float rsum = 0.f;
    f32x4 oacc[4];
    #pragma unroll
    for (int ct = 0; ct < 4; ++ct) oacc[ct] = f32x4{0.f, 0.f, 0.f, 0.f};

    #pragma unroll
    for (int nc = 0; nc < 8; ++nc) {
        const int db = nc & 1;
        // issue next chunk's DMA first — whole compute phase covers latency
        if (nc < 7) { STAGE(nc + 1, db ^ 1); }
        // ---- QK from LDS (swizzled reads) ----
        const __bf16* Kcur = Kbw + db*4096;
        f32x4 accs[4];
        #pragma unroll
        for (int sub = 0; sub < 4; ++sub) {
            const __bf16* kr = Kcur + (sub*16 + lg)*64;
            bf16x8 a0 = *(const bf16x8*)&kr[sw0];
            bf16x8 a1 = *(const bf16x8*)&kr[sw1];
            f32x4 acc = {0.f, 0.f, 0.f, 0.f};
            acc = __builtin_amdgcn_mfma_f32_16x16x32_bf16(a0, bfrag0, acc, 0, 0, 0);
            acc = __builtin_amdgcn_mfma_f32_16x16x32_bf16(a1, bfrag1, acc, 0, 0, 0);
            accs[sub] = acc;
        }
        // ---- exp, pack, rsum, Elds ----
        #pragma unroll
        for (int sub = 0; sub < 4; ++sub) {
            float p0 = __builtin_exp2f(accs[sub][0] * EC);
            float p1 = __builtin_exp2f(accs[sub][1] * EC);
            float p2 = __builtin_exp2f(accs[sub][2] * EC);
            float p3 = __builtin_exp2f(accs[sub][3] * EC);
            rsum += (p0 + p1) + (p2 + p3);
            u32x2 pk;
            pk.x = bpack(p0, p1);
            pk.y = bpack(p2, p3);
            ppk[nc][sub] = pk;
            *(u32x2*)&eldw[lg*80 + sub*16 + g*4] = pk;
        }
        // ---- PV from LDS (swizzled V reads) ----
        const __bf16* er = &eldw[lg*80];
        bf16x8 pf0 = *(const bf16x8*)&er[g*8];
        bf16x8 pf1 = *(const bf16x8*)&er[g*8 + 32];
        const __bf16* Vcur = Vbw + db*4096;
        #pragma unroll
        for (int ct = 0; ct < 4; ++ct) {
            const __bf16* vr = Vcur + (ct*16 + lg)*64;
            bf16x8 v0 = *(const bf16x8*)&vr[sw0];
            bf16x8 v1 = *(const bf16x8*)&vr[sw1];
            oacc[ct] = __builtin_amdgcn_mfma_f32_16x16x32_bf16(v0, pf0, oacc[ct], 0, 0, 0);
            oacc[ct] = __builtin_amdgcn_mfma_f32_16x16x32_bf16(v1, pf1, oacc[ct], 0, 0, 0);
        }
        // ---- single barrier per chunk: drains DMA (vmcnt) + LDS ops ----
        __syncthreads();
    }

    // ---- cross-wave rsum reduce ----
    rsum += __shfl_xor(rsum, 16);
    rsum += __shfl_xor(rsum, 32);
    if (l < 16) rsb[(nh*2 + strip)*16 + l] = rsum;
    __syncthreads();
    const float rinv = 1.0f / (rsb[(0*2 + strip)*16 + lg] + rsb[(1*2 + strip)*16 + lg]);

    // ---- O: scale, cross-wave reduce (Obuf aliases staging region) ----
    #pragma unroll
    for (int ct = 0; ct < 4; ++ct) oacc[ct] *= rinv;

    const int rr = l >> 4, cc = l & 15;
    if (nh == 1) {
        #pragma unroll
        for (int ct = 0; ct < 4; ++ct)
            *(f32x4*)&Obuf[(strip*16 + lg)*72 + ct*16 + g*4] = oacc[ct];
    }
    __syncthreads();
    if (nh == 0) {
        #pragma unroll
        for (int ct = 0; ct < 4; ++ct) {
            f32x4 o = *(const f32x4*)&Obuf[(strip*16 + lg)*72 + ct*16 + g*4];
            o = o + oacc[ct];
            *(f32x4*)&Obuf[(strip*16 + lg)*72 + ct*16 + g*4] = o;
        }
    }
    __syncthreads();
    #pragma unroll
    for (int it = 0; it < 2; ++it) {
        int row = it*16 + w*4 + rr;           // 0..31
        f32x4 o = *(const f32x4*)&Obuf[row*72 + cc*4];
        __builtin_nontemporal_store(o,
            (f32x4*)&out[(((size_t)bh*LQ + a0 + row) << 6) + cc*4]);
    }

    // ---- attn store phase: unpack ppk, *rinv, Pt-staged contiguous NT ----
    float* ptw = Pt0 + (size_t)w * 16 * 72;
    float* attnb = out + OUT0_SIZE + ((size_t)bh << 20);
    #pragma unroll
    for (int nc = 0; nc < 8; ++nc) {
        const int nbase = n0w + nc*64;
        #pragma unroll
        for (int sub = 0; sub < 4; ++sub) {
            unsigned lo = ppk[nc][sub].x, hi = ppk[nc][sub].y;
            f32x4 ps;
            ps[0] = __builtin_bit_cast(float, lo << 16) * rinv;
            ps[1] = __builtin_bit_cast(float, lo & 0xffff0000u) * rinv;
            ps[2] = __builtin_bit_cast(float, hi << 16) * rinv;
            ps[3] = __builtin_bit_cast(float, hi & 0xffff0000u) * rinv;
            *(f32x4*)&ptw[lg*72 + sub*16 + g*4] = ps;
        }
        #pragma unroll
        for (int it = 0; it < 4; ++it) {
            int row = it*4 + rr;
            f32x4 pp = *(const f32x4*)&ptw[row*72 + cc*4];
            __builtin_nontemporal_store(pp,
                (f32x4*)&attnb[((size_t)(qbase + row) << 10) + nbase + cc*4]);
        }
    }
#undef STAGE
}

// ---------------------------------------------------------------------------
extern "C" void kernel_launch(void* const* d_in, const int* in_sizes, int n_in,
                              void* d_out, int out_size, void* d_ws, size_t ws_size,
                              hipStream_t stream) {
    const float* q   = (const float*)d_in[0];
    const float* WA  = (const float*)d_in[1];
    const float* WB  = (const float*)d_in[2];
    const float* WAt = (const float*)d_in[3];
    const float* WBt = (const float*)d_in[4];
    const float* Wav = (const float*)d_in[5];
    const float* Wbv = (const float*)d_in[6];
    const float* qt  = (const float*)d_in[7];
    const float* v   = (const float*)d_in[8];
    float* out = (float*)d_out;

    char* ws = (char*)d_ws;
    float*  W    = (float*)(ws);                          // 128 KB
    float*  Wv   = (float*)(ws + 131072);                 // 128 KB
    __bf16* qW   = (__bf16*)(ws + 262144);                // 8 MB
    __bf16* qtT  = (__bf16*)(ws + 262144 + 8388608);      // 8 MB
    __bf16* vWT  = (__bf16*)(ws + 262144 + 2*8388608);    // 8 MB (tiled)
    float*  P1   = (float*)(ws + 262144);                 // 128 KB (aliases qW)
    float*  P2   = (float*)(ws + 262144 + 131072);        // 128 KB

    hipLaunchKernelGGL(fold_pairs, dim3(24), dim3(256), 0, stream,
                       WA, WB, WBt, WAt, Wav, Wbv, P1, P2, Wv);
    hipLaunchKernelGGL(fold_final, dim3(8),  dim3(256), 0, stream, P1, P2, W);
    hipLaunchKernelGGL(prepass,    dim3(64, 40), dim3(256), 0, stream,
                       q, W, qt, v, Wv, qW, qtT, vWT);
    hipLaunchKernelGGL(attn_kernel, dim3(2048), dim3(256), 0, stream,
                       qW, qtT, vWT, out);
}